// Round 5
// baseline (334.152 us; speedup 1.0000x reference)
//
#include <hip/hip_runtime.h>
#include <math.h>

namespace {
constexpr int Bn = 8, Cn = 3, Hn = 512, Wn = 960;
constexpr int RS = 8;                 // output rows per strip
constexpr int SR = RS + 2;            // staged rows (strip + halo)
constexpr int TPB = 256;              // 4 waves
constexpr int NT = 240;               // active threads: 4 cols each = 960
constexpr int ROWF = 968;             // LDS row floats; col x -> idx x+4; borders at 3, 964
constexpr int NSTRIP = Hn / RS;       // 64
constexpr int NBLK = NSTRIP * Bn * Cn;// 1536
constexpr float kC1 = 1e-4f;          // 0.01^2
constexpr float kC2 = 9e-4f;          // 0.03^2
constexpr float kEps2 = 1e-6f;        // 0.001^2
constexpr float A3 = 0.85f / 3.f;     // alpha/3
constexpr float B3 = 0.05f;           // (1-alpha)/3
}

__device__ __forceinline__ float gath1(const float* __restrict__ row, float xs) {
    float xf = floorf(xs);
    float wx = xs - xf;
    int xi = (int)xf;
    int a0 = min(max(xi, 0), Wn - 1);
    int a1 = min(max(xi + 1, 0), Wn - 1);
    return (1.f - wx) * row[a0] + wx * row[a1];
}

__global__ __launch_bounds__(TPB, 4) void stereo_fused(
    const float* __restrict__ left, const float* __restrict__ right,
    const float* __restrict__ d_left, const float* __restrict__ d_right,
    const float* __restrict__ nonocc, float* __restrict__ acc,
    float* __restrict__ out)
{
    __shared__ float sW[SR][ROWF];     // warped right, ONE channel (this block's)
    __shared__ float red[3][TPB / 64];

    const int t = threadIdx.x;
    const int strip = blockIdx.x;
    const int b = blockIdx.y;
    const int c = blockIdx.z;
    const int y0 = strip * RS;
    const bool act = (t < NT);
    const int x0 = t * 4;              // first of this thread's 4 columns

    const float* dL = d_left  + (size_t)b * Hn * Wn;
    const float* dR = d_right + (size_t)b * Hn * Wn;
    const float* no = nonocc  + (size_t)b * Hn * Wn;
    const float* lchan = left  + ((size_t)b * Cn + c) * Hn * Wn;
    const float* rchan = right + ((size_t)b * Cn + c) * Hn * Wn;

    // zero-pad border columns (never overwritten by staging)
    if (t == NT) {
        #pragma unroll
        for (int r = 0; r < SR; ++r) sW[r][3] = 0.f;
    }
    if (t == NT + 1) {
        #pragma unroll
        for (int r = 0; r < SR; ++r) sW[r][964] = 0.f;
    }

    // ---- stage warped right (this channel) into LDS ----
    #pragma unroll 2
    for (int r = 0; r < SR; ++r) {
        if (!act) break;
        int y = y0 - 1 + r;
        float4 wv = {0.f, 0.f, 0.f, 0.f};
        if (y >= 0 && y < Hn) {        // wave-uniform
            const float4 d4 = *(const float4*)(dL + (size_t)y * Wn + x0);
            const float* rrow = rchan + (size_t)y * Wn;
            wv.x = gath1(rrow, (float)(x0 + 0) - d4.x);
            wv.y = gath1(rrow, (float)(x0 + 1) - d4.y);
            wv.z = gath1(rrow, (float)(x0 + 2) - d4.z);
            wv.w = gath1(rrow, (float)(x0 + 3) - d4.w);
        }
        *(float4*)&sW[r][x0 + 4] = wv;
    }
    __syncthreads();

    float p_sum = 0.f, v_sum = 0.f, l_sum = 0.f;

    if (act) {
        float lL[3][6], wW[3][6];      // vertical ring: 3 rows x 6 cols (x0-1 .. x0+4)

        auto loadRow = [&](int slot, int r) {
            int y = y0 - 1 + r;
            int yy = min(max(y, 0), Hn - 1);
            float ym = (y >= 0 && y < Hn) ? 1.f : 0.f;
            const float* lrow = lchan + (size_t)yy * Wn;
            float4 lm = *(const float4*)(lrow + x0);
            lL[slot][0] = (x0 > 0) ? lrow[x0 - 1] * ym : 0.f;
            lL[slot][1] = lm.x * ym;
            lL[slot][2] = lm.y * ym;
            lL[slot][3] = lm.z * ym;
            lL[slot][4] = lm.w * ym;
            lL[slot][5] = (x0 + 4 < Wn) ? lrow[x0 + 4] * ym : 0.f;
            float4 wm = *(const float4*)&sW[r][x0 + 4];
            wW[slot][0] = sW[r][x0 + 3];
            wW[slot][1] = wm.x;
            wW[slot][2] = wm.y;
            wW[slot][3] = wm.z;
            wW[slot][4] = wm.w;
            wW[slot][5] = sW[r][x0 + 8];
        };

        loadRow(0, 0);
        loadRow(1, 1);

        #pragma unroll
        for (int k = 0; k < RS; ++k) {
            const int rn = k + 2;
            const int sn = rn % 3;     // slot for the new row
            const int sc = (k + 1) % 3;// slot holding the center row (y0+k)
            loadRow(sn, rn);

            // column sums over the 3-row window for the 6 columns
            float cx[6], cy[6], cxx[6], cyy[6], cxy[6];
            #pragma unroll
            for (int q = 0; q < 6; ++q) {
                float l0 = lL[0][q], l1 = lL[1][q], l2 = lL[2][q];
                float w0 = wW[0][q], w1 = wW[1][q], w2 = wW[2][q];
                cx[q] = l0 + l1 + l2;
                cy[q] = w0 + w1 + w2;
                cxx[q] = fmaf(l0, l0, fmaf(l1, l1, l2 * l2));
                cyy[q] = fmaf(w0, w0, fmaf(w1, w1, w2 * w2));
                cxy[q] = fmaf(l0, w0, fmaf(l1, w1, l2 * w2));
            }

            int y = y0 + k;
            float inv_cy = (y == 0 || y == Hn - 1) ? 0.5f : (1.f / 3.f);
            float4 d4 = *(const float4*)(dL + (size_t)y * Wn + x0);
            float4 n4 = *(const float4*)(no + (size_t)y * Wn + x0);
            float da[4] = {d4.x, d4.y, d4.z, d4.w};
            float na[4] = {n4.x, n4.y, n4.z, n4.w};
            const float* drow = dR + (size_t)y * Wn;

            #pragma unroll
            for (int j = 0; j < 4; ++j) {
                float Sx  = cx[j]  + cx[j + 1]  + cx[j + 2];
                float Sy  = cy[j]  + cy[j + 1]  + cy[j + 2];
                float Sxx = cxx[j] + cxx[j + 1] + cxx[j + 2];
                float Syy = cyy[j] + cyy[j + 1] + cyy[j + 2];
                float Sxy = cxy[j] + cxy[j + 1] + cxy[j + 2];
                int xg = x0 + j;
                float inv = inv_cy * ((xg == 0 || xg == Wn - 1) ? 0.5f : (1.f / 3.f));
                float mu_x = Sx * inv, mu_y = Sy * inv;
                float sig_x  = Sxx * inv - mu_x * mu_x;
                float sig_y  = Syy * inv - mu_y * mu_y;
                float sig_xy = Sxy * inv - mu_x * mu_y;
                float num = (2.f * mu_x * mu_y + kC1) * (2.f * sig_xy + kC2);
                float den = (mu_x * mu_x + mu_y * mu_y + kC1) * (sig_x + sig_y + kC2);
                float ssim = num / (den + 1e-12f);
                float sm = fminf(fmaxf(0.5f * (1.f - ssim), 0.f), 1.f);
                float lc = lL[sc][j + 1], wc = wW[sc][j + 1];
                float df = lc - wc;
                float l1v = sqrtf(df * df + kEps2);

                float dv = da[j];
                float xs = (float)xg - dv;
                float gx = 2.f * xs / (float)(Wn - 1) - 1.f;
                float vmask = (gx >= -1.f && gx <= 1.f) ? 1.f : 0.f;
                float vw = vmask * na[j];

                p_sum += (A3 * sm + B3 * l1v) * vw;
                if (c == 0) {          // block-uniform: LR + valid sums once
                    v_sum += vw;
                    float drw = gath1(drow, xs);
                    float ddv = dv - drw;
                    l_sum += sqrtf(ddv * ddv + kEps2) * vw;
                }
            }
        }
    }

    // ---- block reduction -> global atomics -> ticketed finalize ----
    #pragma unroll
    for (int off = 32; off > 0; off >>= 1) {
        p_sum += __shfl_down(p_sum, off);
        v_sum += __shfl_down(v_sum, off);
        l_sum += __shfl_down(l_sum, off);
    }
    int lane = t & 63, wv = t >> 6;
    if (lane == 0) { red[0][wv] = p_sum; red[1][wv] = v_sum; red[2][wv] = l_sum; }
    __syncthreads();
    if (t == 0) {
        float P = 0.f, V = 0.f, L = 0.f;
        #pragma unroll
        for (int i = 0; i < TPB / 64; ++i) { P += red[0][i]; V += red[1][i]; L += red[2][i]; }
        atomicAdd(&acc[0], P);
        atomicAdd(&acc[1], V);
        atomicAdd(&acc[2], L);
        __threadfence();
        unsigned prev = atomicAdd((unsigned*)&acc[3], 1u);
        if (prev == NBLK - 1) {        // last block finalizes
            float Pa = atomicAdd(&acc[0], 0.f);
            float Va = atomicAdd(&acc[1], 0.f);
            float La = atomicAdd(&acc[2], 0.f);
            float photo = Pa / (Va + 1e-6f);
            float lr = La / (Va + 1e-6f);
            out[0] = photo + 0.2f * lr;   // W_PHOTO=1, W_LR=0.2
            out[1] = photo;
            out[2] = lr;
            out[3] = Va * (1.f / (float)(Bn * Hn * Wn));
        }
    }
}

extern "C" void kernel_launch(void* const* d_in, const int* in_sizes, int n_in,
                              void* d_out, int out_size, void* d_ws, size_t ws_size,
                              hipStream_t stream) {
    const float* left   = (const float*)d_in[0];
    const float* right  = (const float*)d_in[1];
    const float* dl     = (const float*)d_in[2];
    const float* dr     = (const float*)d_in[3];
    const float* nonocc = (const float*)d_in[4];
    float* acc = (float*)d_ws;
    float* out = (float*)d_out;

    hipMemsetAsync(acc, 0, 4 * sizeof(float), stream);
    dim3 grid(NSTRIP, Bn, Cn);
    stereo_fused<<<grid, TPB, 0, stream>>>(left, right, dl, dr, nonocc, acc, out);
}